// Round 1
// baseline (3515.759 us; speedup 1.0000x reference)
//
#include <hip/hip_runtime.h>
#include <hip/hip_bf16.h>
#include <math.h>

// ---------- types ----------
typedef __bf16 bf16x8 __attribute__((ext_vector_type(8)));
typedef float  f32x4  __attribute__((ext_vector_type(4)));
typedef unsigned short us8 __attribute__((ext_vector_type(8)));

__device__ __forceinline__ unsigned short f2bf(float x) {
  unsigned int u = __float_as_uint(x);
  u += 0x7FFFu + ((u >> 16) & 1u);          // RNE
  return (unsigned short)(u >> 16);
}
__device__ __forceinline__ float bf2f(unsigned short v) {
  return __uint_as_float(((unsigned int)v) << 16);
}

// Problem constants (fixed by setup_inputs): B=32, V=4, P=784, D=768
// folded rows n = bp*4 + v, bp = b*784 + p, token lives at x[b, v*784+p, :]
// NROW = 100352 = 784*128 (exact 128-multiple), D=768, 3D=2304, 4D=3072

// ---------- f32 -> bf16 convert (weights) ----------
__global__ __launch_bounds__(256) void conv_f32_bf16(const float* __restrict__ s,
                                                     unsigned short* __restrict__ d, int n4) {
  int i = blockIdx.x * 256 + threadIdx.x;
  if (i >= n4) return;
  float4 f = ((const float4*)s)[i];
  ushort4 u;
  u.x = f2bf(f.x); u.y = f2bf(f.y); u.z = f2bf(f.z); u.w = f2bf(f.w);
  ((ushort4*)d)[i] = u;
}

// ---------- LayerNorm: read permuted fp32 row, write bf16 row ----------
__global__ __launch_bounds__(256) void ln_kernel(const float* __restrict__ src,
                                                 const float* __restrict__ w,
                                                 const float* __restrict__ b,
                                                 unsigned short* __restrict__ dst) {
  const int wv = threadIdx.x >> 6;
  const int lane = threadIdx.x & 63;
  const int n = blockIdx.x * 4 + wv;            // token row 0..100351
  const int bp = n >> 2, v = n & 3;
  const int bb = bp / 784, p = bp - bb * 784;
  const float* row = src + ((size_t)bb * 3136 + (size_t)v * 784 + p) * 768;
  float4 x0 = ((const float4*)row)[lane];
  float4 x1 = ((const float4*)row)[lane + 64];
  float4 x2 = ((const float4*)row)[lane + 128];
  float s  = x0.x + x0.y + x0.z + x0.w + x1.x + x1.y + x1.z + x1.w
           + x2.x + x2.y + x2.z + x2.w;
  float ss = x0.x*x0.x + x0.y*x0.y + x0.z*x0.z + x0.w*x0.w
           + x1.x*x1.x + x1.y*x1.y + x1.z*x1.z + x1.w*x1.w
           + x2.x*x2.x + x2.y*x2.y + x2.z*x2.z + x2.w*x2.w;
  #pragma unroll
  for (int off = 32; off > 0; off >>= 1) {
    s  += __shfl_xor(s,  off, 64);
    ss += __shfl_xor(ss, off, 64);
  }
  const float mu   = s * (1.0f / 768.0f);
  const float rstd = rsqrtf(ss * (1.0f / 768.0f) - mu * mu + 1e-5f);
  unsigned short* drow = dst + (size_t)n * 768;
  {
    float4 w4 = ((const float4*)w)[lane];
    float4 b4 = ((const float4*)b)[lane];
    ushort4 u;
    u.x = f2bf((x0.x - mu) * rstd * w4.x + b4.x);
    u.y = f2bf((x0.y - mu) * rstd * w4.y + b4.y);
    u.z = f2bf((x0.z - mu) * rstd * w4.z + b4.z);
    u.w = f2bf((x0.w - mu) * rstd * w4.w + b4.w);
    ((ushort4*)drow)[lane] = u;
  }
  {
    float4 w4 = ((const float4*)w)[lane + 64];
    float4 b4 = ((const float4*)b)[lane + 64];
    ushort4 u;
    u.x = f2bf((x1.x - mu) * rstd * w4.x + b4.x);
    u.y = f2bf((x1.y - mu) * rstd * w4.y + b4.y);
    u.z = f2bf((x1.z - mu) * rstd * w4.z + b4.z);
    u.w = f2bf((x1.w - mu) * rstd * w4.w + b4.w);
    ((ushort4*)drow)[lane + 64] = u;
  }
  {
    float4 w4 = ((const float4*)w)[lane + 128];
    float4 b4 = ((const float4*)b)[lane + 128];
    ushort4 u;
    u.x = f2bf((x2.x - mu) * rstd * w4.x + b4.x);
    u.y = f2bf((x2.y - mu) * rstd * w4.y + b4.y);
    u.z = f2bf((x2.z - mu) * rstd * w4.z + b4.z);
    u.w = f2bf((x2.w - mu) * rstd * w4.w + b4.w);
    ((ushort4*)drow)[lane + 128] = u;
  }
}

// ---------- GEMM: C = A(bf16, MxK) * B(bf16, NxK)^T + epilogue ----------
// m97 structure: 128x128 tile, BK=64, 4 waves each 64x64, 16x16x32 bf16 MFMA,
// global_load_lds width=16, XOR-swizzled LDS (16B-block index ^ (row&7)) to
// avoid the all-lanes-same-bank ds_read_b128 pattern while keeping the
// wave-uniform-base + lane*16B DMA contract (swizzle folded into the GLOBAL
// column each lane fetches).
// EPI: 0 = +bias -> qkv bf16 in [bp][seg][h][v][96] layout
//      1 = +bias +x residual -> d_out fp32 (unfolded addr)
//      2 = +bias, gelu-erf -> bf16 row-major (N cols)
//      3 = +bias +d_out residual -> d_out fp32 (unfolded addr)
template <int K, int EPI>
__global__ __launch_bounds__(256) void gemm_k(const unsigned short* __restrict__ A,
                                              const unsigned short* __restrict__ Bm,
                                              const float* __restrict__ bias,
                                              void* __restrict__ outp,
                                              const float* __restrict__ aux,
                                              int N) {
  __shared__ unsigned short sA[128 * 64];
  __shared__ unsigned short sB[128 * 64];
  const int tid  = threadIdx.x;
  const int w    = tid >> 6;
  const int lane = tid & 63;
  const int quad = lane >> 4;
  const int l16  = lane & 15;
  const int wm = w >> 1, wn = w & 1;
  const int bx = blockIdx.x, by = blockIdx.y;

  // staging: lane (r8, cb) loads global 16B block (cb ^ r8) of its row so that
  // the hardware lane*16B LDS placement realizes the swizzled layout.
  const int r8 = lane >> 3;
  const int cb = lane & 7;
  const int swo = ((cb ^ r8) << 3);
  const unsigned short* gA = A  + (size_t)(by * 128 + r8) * K + swo;
  const unsigned short* gB = Bm + (size_t)(bx * 128 + r8) * K + swo;

  f32x4 acc[4][4];
  #pragma unroll
  for (int i = 0; i < 4; ++i)
    #pragma unroll
    for (int j = 0; j < 4; ++j) {
      f32x4 z = {0.0f, 0.0f, 0.0f, 0.0f};
      acc[i][j] = z;
    }

  for (int k0 = 0; k0 < K; k0 += 64) {
    #pragma unroll
    for (int i = 0; i < 4; ++i) {
      const int chunk = w * 4 + i;                 // 0..15, wave-uniform
      __builtin_amdgcn_global_load_lds(
          (__attribute__((address_space(1))) void*)(gA + (size_t)(chunk * 8) * K + k0),
          (__attribute__((address_space(3))) void*)(&sA[chunk * 512]), 16, 0, 0);
      __builtin_amdgcn_global_load_lds(
          (__attribute__((address_space(1))) void*)(gB + (size_t)(chunk * 8) * K + k0),
          (__attribute__((address_space(3))) void*)(&sB[chunk * 512]), 16, 0, 0);
    }
    __syncthreads();   // compiler emits s_waitcnt vmcnt(0) before s_barrier

    #pragma unroll
    for (int kk = 0; kk < 2; ++kk) {
      bf16x8 af[4], bfr[4];
      const int q = kk * 4 + quad;
      #pragma unroll
      for (int mi = 0; mi < 4; ++mi) {
        const int m = wm * 64 + mi * 16 + l16;
        af[mi] = *(const bf16x8*)(&sA[m * 64 + ((q ^ (m & 7)) << 3)]);
      }
      #pragma unroll
      for (int ni = 0; ni < 4; ++ni) {
        const int n = wn * 64 + ni * 16 + l16;
        bfr[ni] = *(const bf16x8*)(&sB[n * 64 + ((q ^ (n & 7)) << 3)]);
      }
      #pragma unroll
      for (int mi = 0; mi < 4; ++mi)
        #pragma unroll
        for (int ni = 0; ni < 4; ++ni)
          acc[mi][ni] = __builtin_amdgcn_mfma_f32_16x16x32_bf16(af[mi], bfr[ni],
                                                                acc[mi][ni], 0, 0, 0);
    }
    __syncthreads();
  }

  // epilogue: C/D layout col=lane&15, row=quad*4+reg  [m89-verified]
  #pragma unroll
  for (int mi = 0; mi < 4; ++mi) {
    #pragma unroll
    for (int ni = 0; ni < 4; ++ni) {
      const int row0 = by * 128 + wm * 64 + mi * 16 + quad * 4;
      const int col  = bx * 128 + wn * 64 + ni * 16 + l16;
      const float bia = bias[col];
      #pragma unroll
      for (int r = 0; r < 4; ++r) {
        const int rr = row0 + r;
        float val = acc[mi][ni][r] + bia;
        if (EPI == 0) {
          // qkv -> [bp][seg(q/k/v)][h][v][96] bf16 (attention-friendly)
          int seg = col / 768;
          int cc  = col - seg * 768;
          int hh  = cc / 96;
          int dd  = cc - hh * 96;
          int bp = rr >> 2, v = rr & 3;
          size_t addr = (size_t)bp * 9216 + (size_t)seg * 3072 + hh * 384 + v * 96 + dd;
          ((unsigned short*)outp)[addr] = f2bf(val);
        } else if (EPI == 1 || EPI == 3) {
          // residual add, write fp32 to d_out at unfolded position
          int bp = rr >> 2, v = rr & 3;
          int bb = bp / 784, p = bp - bb * 784;
          size_t addr = ((size_t)bb * 3136 + (size_t)v * 784 + p) * 768 + col;
          ((float*)outp)[addr] = val + aux[addr];
        } else { // EPI == 2: exact-erf GELU -> bf16 row-major
          size_t addr = (size_t)rr * N + col;
          float g = 0.5f * val * (1.0f + erff(val * 0.7071067811865475f));
          ((unsigned short*)outp)[addr] = f2bf(g);
        }
      }
    }
  }
}

// ---------- tiny cross-view attention: one thread per (bp, head, vq) ----------
// qs layout [bp][seg][h][v][96] bf16; o written as rows n=bp*4+vq, 768 cols.
__global__ __launch_bounds__(256) void attn_kernel(const unsigned short* __restrict__ qs,
                                                   unsigned short* __restrict__ o) {
  int idx = blockIdx.x * 256 + threadIdx.x;   // 25088*32 total
  int vq = idx & 3;
  int h  = (idx >> 2) & 7;
  int bp = idx >> 5;
  const unsigned short* qp = qs + (size_t)bp * 9216 + h * 384 + vq * 96;
  const unsigned short* kp = qs + (size_t)bp * 9216 + 3072 + h * 384;
  const unsigned short* vp = qs + (size_t)bp * 9216 + 6144 + h * 384;
  float s0 = 0.f, s1 = 0.f, s2 = 0.f, s3 = 0.f;
  #pragma unroll
  for (int c = 0; c < 96; c += 8) {
    us8 q8 = *(const us8*)(qp + c);
    us8 k0 = *(const us8*)(kp + c);
    us8 k1 = *(const us8*)(kp + 96 + c);
    us8 k2 = *(const us8*)(kp + 192 + c);
    us8 k3 = *(const us8*)(kp + 288 + c);
    #pragma unroll
    for (int j = 0; j < 8; ++j) {
      float qf = bf2f(q8[j]);
      s0 += qf * bf2f(k0[j]);
      s1 += qf * bf2f(k1[j]);
      s2 += qf * bf2f(k2[j]);
      s3 += qf * bf2f(k3[j]);
    }
  }
  const float scale = 0.10206207261596575f;  // 1/sqrt(96)
  s0 *= scale; s1 *= scale; s2 *= scale; s3 *= scale;
  float m = fmaxf(fmaxf(s0, s1), fmaxf(s2, s3));
  float e0 = __expf(s0 - m), e1 = __expf(s1 - m), e2 = __expf(s2 - m), e3 = __expf(s3 - m);
  float inv = 1.0f / (e0 + e1 + e2 + e3);
  e0 *= inv; e1 *= inv; e2 *= inv; e3 *= inv;
  unsigned short* op = o + (size_t)(bp * 4 + vq) * 768 + h * 96;
  #pragma unroll
  for (int c = 0; c < 96; c += 8) {
    us8 v0 = *(const us8*)(vp + c);
    us8 v1 = *(const us8*)(vp + 96 + c);
    us8 v2 = *(const us8*)(vp + 192 + c);
    us8 v3 = *(const us8*)(vp + 288 + c);
    us8 r;
    #pragma unroll
    for (int j = 0; j < 8; ++j) {
      float val = e0 * bf2f(v0[j]) + e1 * bf2f(v1[j]) + e2 * bf2f(v2[j]) + e3 * bf2f(v3[j]);
      r[j] = f2bf(val);
    }
    *(us8*)(op + c) = r;
  }
}

// ---------- launch ----------
extern "C" void kernel_launch(void* const* d_in, const int* in_sizes, int n_in,
                              void* d_out, int out_size, void* d_ws, size_t ws_size,
                              hipStream_t stream) {
  const float* x         = (const float*)d_in[0];
  const float* norm1_w   = (const float*)d_in[2];
  const float* norm1_b   = (const float*)d_in[3];
  const float* in_proj_w = (const float*)d_in[4];
  const float* in_proj_b = (const float*)d_in[5];
  const float* out_w     = (const float*)d_in[6];
  const float* out_b     = (const float*)d_in[7];
  const float* norm2_w   = (const float*)d_in[8];
  const float* norm2_b   = (const float*)d_in[9];
  const float* ffn_w1    = (const float*)d_in[10];
  const float* ffn_b1    = (const float*)d_in[11];
  const float* ffn_w2    = (const float*)d_in[12];
  const float* ffn_b2    = (const float*)d_in[13];
  float* out = (float*)d_out;

  // workspace layout (all offsets 256B-aligned):
  //   wq : 100352*3072 bf16 (616,562,688 B)  — qkv (as [bp][seg][h][v][96]) then gelu acts
  //   wh : 100352*768  bf16 (154,140,672 B)  — h1 -> o -> h2 (sequentially dead)
  //   wB : bf16 weights (14,155,776 B)
  char* ws = (char*)d_ws;
  unsigned short* wq = (unsigned short*)ws;
  unsigned short* wh = (unsigned short*)(ws + 616562688u);
  unsigned short* wB = (unsigned short*)(ws + 616562688u + 154140672u);
  unsigned short* wIn  = wB;
  unsigned short* wOut = wB + 1769472;
  unsigned short* wF1  = wOut + 589824;
  unsigned short* wF2  = wF1 + 2359296;

  conv_f32_bf16<<<(442368 + 255) / 256, 256, 0, stream>>>(in_proj_w, wIn, 442368);
  conv_f32_bf16<<<(147456 + 255) / 256, 256, 0, stream>>>(out_w, wOut, 147456);
  conv_f32_bf16<<<(589824 + 255) / 256, 256, 0, stream>>>(ffn_w1, wF1, 589824);
  conv_f32_bf16<<<(589824 + 255) / 256, 256, 0, stream>>>(ffn_w2, wF2, 589824);

  // LN1: x (permuted read) -> wh
  ln_kernel<<<25088, 256, 0, stream>>>(x, norm1_w, norm1_b, wh);
  // QKV: wh(100352x768) @ in_proj_w^T (2304x768) -> wq (attention layout)
  gemm_k<768, 0><<<dim3(18, 784), 256, 0, stream>>>(wh, wIn, in_proj_b, (void*)wq, nullptr, 2304);
  // attention: wq -> wh (o, bf16 rows)
  attn_kernel<<<3136, 256, 0, stream>>>(wq, wh);
  // out-proj + residual(x): wh @ out_w^T -> d_out fp32 (unfolded)
  gemm_k<768, 1><<<dim3(6, 784), 256, 0, stream>>>(wh, wOut, out_b, (void*)out, x, 768);
  // LN2: d_out (permuted read) -> wh
  ln_kernel<<<25088, 256, 0, stream>>>(out, norm2_w, norm2_b, wh);
  // FFN1 + gelu: wh @ ffn_w1^T (3072x768) -> wq bf16 row-major
  gemm_k<768, 2><<<dim3(24, 784), 256, 0, stream>>>(wh, wF1, ffn_b1, (void*)wq, nullptr, 3072);
  // FFN2 + residual(d_out): wq(100352x3072) @ ffn_w2^T (768x3072) -> d_out fp32
  gemm_k<3072, 3><<<dim3(6, 784), 256, 0, stream>>>(wq, wF2, ffn_b2, (void*)out, out, 768);

  (void)in_sizes; (void)n_in; (void)out_size; (void)ws_size; (void)norm2_w; (void)norm2_b;
}

// Round 2
// 3312.415 us; speedup vs baseline: 1.0614x; 1.0614x over previous
//
#include <hip/hip_runtime.h>
#include <hip/hip_bf16.h>
#include <math.h>

// ---------- types ----------
typedef __bf16 bf16x8 __attribute__((ext_vector_type(8)));
typedef float  f32x4  __attribute__((ext_vector_type(4)));
typedef unsigned short us8 __attribute__((ext_vector_type(8)));
typedef unsigned short us4 __attribute__((ext_vector_type(4)));

__device__ __forceinline__ unsigned short f2bf(float x) {
  unsigned int u = __float_as_uint(x);
  u += 0x7FFFu + ((u >> 16) & 1u);          // RNE
  return (unsigned short)(u >> 16);
}
__device__ __forceinline__ float bf2f(unsigned short v) {
  return __uint_as_float(((unsigned int)v) << 16);
}
// tanh-form GELU: max |diff vs erf-gelu| ~1e-3, harmless vs 0.1275 threshold
__device__ __forceinline__ float gelu_t(float x) {
  float y = 0.7978845608028654f * x * (1.0f + 0.044715f * x * x);
  float e = __expf(2.0f * y);               // y<<0 -> e->0 -> result 0; y>>0 -> x
  return x - x / (e + 1.0f);
}

// Problem constants: B=32, V=4, P=784, D=768; rows n = bp*4+v, bp=b*784+p
// NROW = 100352 = 784*128; grid.y is always 784 (=8 XCDs * 98)

// ---------- f32 -> bf16 convert (weights) ----------
__global__ __launch_bounds__(256) void conv_f32_bf16(const float* __restrict__ s,
                                                     unsigned short* __restrict__ d, int n4) {
  int i = blockIdx.x * 256 + threadIdx.x;
  if (i >= n4) return;
  float4 f = ((const float4*)s)[i];
  ushort4 u;
  u.x = f2bf(f.x); u.y = f2bf(f.y); u.z = f2bf(f.z); u.w = f2bf(f.w);
  ((ushort4*)d)[i] = u;
}

// ---------- LayerNorm: read permuted fp32 row, write bf16 row ----------
__global__ __launch_bounds__(256) void ln_kernel(const float* __restrict__ src,
                                                 const float* __restrict__ w,
                                                 const float* __restrict__ b,
                                                 unsigned short* __restrict__ dst) {
  const int wv = threadIdx.x >> 6;
  const int lane = threadIdx.x & 63;
  const int n = blockIdx.x * 4 + wv;            // token row 0..100351
  const int bp = n >> 2, v = n & 3;
  const int bb = bp / 784, p = bp - bb * 784;
  const float* row = src + ((size_t)bb * 3136 + (size_t)v * 784 + p) * 768;
  float4 x0 = ((const float4*)row)[lane];
  float4 x1 = ((const float4*)row)[lane + 64];
  float4 x2 = ((const float4*)row)[lane + 128];
  float s  = x0.x + x0.y + x0.z + x0.w + x1.x + x1.y + x1.z + x1.w
           + x2.x + x2.y + x2.z + x2.w;
  float ss = x0.x*x0.x + x0.y*x0.y + x0.z*x0.z + x0.w*x0.w
           + x1.x*x1.x + x1.y*x1.y + x1.z*x1.z + x1.w*x1.w
           + x2.x*x2.x + x2.y*x2.y + x2.z*x2.z + x2.w*x2.w;
  #pragma unroll
  for (int off = 32; off > 0; off >>= 1) {
    s  += __shfl_xor(s,  off, 64);
    ss += __shfl_xor(ss, off, 64);
  }
  const float mu   = s * (1.0f / 768.0f);
  const float rstd = rsqrtf(ss * (1.0f / 768.0f) - mu * mu + 1e-5f);
  unsigned short* drow = dst + (size_t)n * 768;
  #pragma unroll
  for (int seg = 0; seg < 3; ++seg) {
    float4 xs = (seg == 0) ? x0 : (seg == 1) ? x1 : x2;
    float4 w4 = ((const float4*)w)[lane + seg * 64];
    float4 b4 = ((const float4*)b)[lane + seg * 64];
    ushort4 u;
    u.x = f2bf((xs.x - mu) * rstd * w4.x + b4.x);
    u.y = f2bf((xs.y - mu) * rstd * w4.y + b4.y);
    u.z = f2bf((xs.z - mu) * rstd * w4.z + b4.z);
    u.w = f2bf((xs.w - mu) * rstd * w4.w + b4.w);
    ((ushort4*)drow)[lane + seg * 64] = u;
  }
}

// ---------- GEMM: C = A(bf16, MxK) * B(bf16, NxK)^T + epilogue ----------
// m97 structure: 128x128 tile, BK=64, 4 waves each 64x64, 16x16x32 bf16 MFMA,
// global_load_lds width=16, XOR-swizzled LDS for conflict-free ds_read_b128.
// XCD remap: grid.y==784==8*98; each XCD owns 98 contiguous row tiles so an
// A row-tile is fetched through exactly one XCD's L2 (perf heuristic only).
// Epilogue: acc -> LDS (two 64-row halves, reuses the 32KB staging LDS) ->
// conflict-free ds_read_b128 -> coalesced vector stores.
// EPI: 0 = +bias -> qkv bf16 in [bp][seg][h][v][96] layout
//      1 = +bias +aux residual -> fp32 (unfolded addr)
//      2 = +bias, gelu -> bf16 row-major (N cols)
//      3 = +bias +aux residual -> fp32 (unfolded addr)
template <int K, int EPI>
__global__ __launch_bounds__(256) void gemm_k(const unsigned short* __restrict__ A,
                                              const unsigned short* __restrict__ Bm,
                                              const float* __restrict__ bias,
                                              void* __restrict__ outp,
                                              const float* __restrict__ aux,
                                              int N) {
  __shared__ unsigned short smem[2 * 128 * 64];   // sA | sB, reused by epilogue
  unsigned short* sA = smem;
  unsigned short* sB = smem + 128 * 64;
  const int tid  = threadIdx.x;
  const int w    = tid >> 6;
  const int lane = tid & 63;
  const int quad = lane >> 4;
  const int l16  = lane & 15;
  const int wm = w >> 1, wn = w & 1;

  // XCD-aware remap (assumes linear-id round-robin over 8 XCDs; perf-only)
  const int gx   = gridDim.x;
  const int flat = blockIdx.y * gx + blockIdx.x;
  const int xcd  = flat & 7;
  const int idx  = flat >> 3;
  const int iby  = idx / gx;
  const int by   = xcd * 98 + iby;
  const int bx   = idx - iby * gx;

  // staging: lane (r8, cb) loads global 16B block (cb ^ r8) of its row so the
  // hardware lane*16B LDS placement realizes the swizzled layout.
  const int r8 = lane >> 3;
  const int cb = lane & 7;
  const int swo = ((cb ^ r8) << 3);
  const unsigned short* gA = A  + (size_t)(by * 128 + r8) * K + swo;
  const unsigned short* gB = Bm + (size_t)(bx * 128 + r8) * K + swo;

  f32x4 acc[4][4];
  #pragma unroll
  for (int i = 0; i < 4; ++i)
    #pragma unroll
    for (int j = 0; j < 4; ++j) {
      f32x4 z = {0.0f, 0.0f, 0.0f, 0.0f};
      acc[i][j] = z;
    }

  for (int k0 = 0; k0 < K; k0 += 64) {
    #pragma unroll
    for (int i = 0; i < 4; ++i) {
      const int chunk = w * 4 + i;                 // 0..15, wave-uniform
      __builtin_amdgcn_global_load_lds(
          (__attribute__((address_space(1))) void*)(gA + (size_t)(chunk * 8) * K + k0),
          (__attribute__((address_space(3))) void*)(&sA[chunk * 512]), 16, 0, 0);
      __builtin_amdgcn_global_load_lds(
          (__attribute__((address_space(1))) void*)(gB + (size_t)(chunk * 8) * K + k0),
          (__attribute__((address_space(3))) void*)(&sB[chunk * 512]), 16, 0, 0);
    }
    __syncthreads();

    #pragma unroll
    for (int kk = 0; kk < 2; ++kk) {
      bf16x8 af[4], bfr[4];
      const int q = kk * 4 + quad;
      #pragma unroll
      for (int mi = 0; mi < 4; ++mi) {
        const int m = wm * 64 + mi * 16 + l16;
        af[mi] = *(const bf16x8*)(&sA[m * 64 + ((q ^ (m & 7)) << 3)]);
      }
      #pragma unroll
      for (int ni = 0; ni < 4; ++ni) {
        const int n = wn * 64 + ni * 16 + l16;
        bfr[ni] = *(const bf16x8*)(&sB[n * 64 + ((q ^ (n & 7)) << 3)]);
      }
      #pragma unroll
      for (int mi = 0; mi < 4; ++mi)
        #pragma unroll
        for (int ni = 0; ni < 4; ++ni)
          acc[mi][ni] = __builtin_amdgcn_mfma_f32_16x16x32_bf16(af[mi], bfr[ni],
                                                                acc[mi][ni], 0, 0, 0);
    }
    __syncthreads();
  }

  // ---- epilogue: LDS restage in two 64-row halves (32KB fp32 each) ----
  float* lsm = (float*)smem;                     // 64 x 128 fp32 = 32 KB
  float biasv[4];
  #pragma unroll
  for (int ni = 0; ni < 4; ++ni) biasv[ni] = bias[bx * 128 + wn * 64 + ni * 16 + l16];

  #pragma unroll
  for (int hf = 0; hf < 2; ++hf) {
    if (wm == hf) {
      #pragma unroll
      for (int mi = 0; mi < 4; ++mi)
        #pragma unroll
        for (int ni = 0; ni < 4; ++ni) {
          const int col_l = wn * 64 + ni * 16 + l16;
          #pragma unroll
          for (int r = 0; r < 4; ++r) {
            const int row_l = mi * 16 + quad * 4 + r;
            lsm[row_l * 128 + col_l] = acc[mi][ni][r] + biasv[ni];
          }
        }
    }
    __syncthreads();
    #pragma unroll
    for (int j = 0; j < 8; ++j) {
      const int cc    = tid + 256 * j;            // float4 chunk 0..2047
      const int row_l = cc >> 5;
      const int col4  = (cc & 31) << 2;
      f32x4 vv = *(const f32x4*)&lsm[row_l * 128 + col4];
      const int rr    = by * 128 + hf * 64 + row_l;
      const int col_g = bx * 128 + col4;
      if (EPI == 0) {
        // qkv -> [bp][seg(q/k/v)][h][v][96] bf16 (4 cols share seg & head)
        const int seg = col_g / 768;
        const int c2  = col_g - seg * 768;
        const int hh  = c2 / 96;
        const int dd  = c2 - hh * 96;
        const int bp = rr >> 2, v = rr & 3;
        us4 u = { f2bf(vv[0]), f2bf(vv[1]), f2bf(vv[2]), f2bf(vv[3]) };
        *(us4*)((unsigned short*)outp + (size_t)bp * 9216 + seg * 3072 + hh * 384 + v * 96 + dd) = u;
      } else if (EPI == 1 || EPI == 3) {
        const int bp = rr >> 2, v = rr & 3;
        const int bb = bp / 784, p = bp - bb * 784;
        const size_t addr = ((size_t)bb * 3136 + (size_t)v * 784 + p) * 768 + col_g;
        f32x4 a4 = *(const f32x4*)(aux + addr);
        vv += a4;
        *(f32x4*)((float*)outp + addr) = vv;
      } else { // EPI == 2: gelu -> bf16 row-major
        us4 u = { f2bf(gelu_t(vv[0])), f2bf(gelu_t(vv[1])),
                  f2bf(gelu_t(vv[2])), f2bf(gelu_t(vv[3])) };
        *(us4*)((unsigned short*)outp + (size_t)rr * N + col_g) = u;
      }
    }
    __syncthreads();
  }
}

// ---------- tiny cross-view attention: one thread per (bp, head, vq) ----------
__global__ __launch_bounds__(256) void attn_kernel(const unsigned short* __restrict__ qs,
                                                   unsigned short* __restrict__ o) {
  int idx = blockIdx.x * 256 + threadIdx.x;   // 25088*32 total
  int vq = idx & 3;
  int h  = (idx >> 2) & 7;
  int bp = idx >> 5;
  const unsigned short* qp = qs + (size_t)bp * 9216 + h * 384 + vq * 96;
  const unsigned short* kp = qs + (size_t)bp * 9216 + 3072 + h * 384;
  const unsigned short* vp = qs + (size_t)bp * 9216 + 6144 + h * 384;
  float s0 = 0.f, s1 = 0.f, s2 = 0.f, s3 = 0.f;
  #pragma unroll
  for (int c = 0; c < 96; c += 8) {
    us8 q8 = *(const us8*)(qp + c);
    us8 k0 = *(const us8*)(kp + c);
    us8 k1 = *(const us8*)(kp + 96 + c);
    us8 k2 = *(const us8*)(kp + 192 + c);
    us8 k3 = *(const us8*)(kp + 288 + c);
    #pragma unroll
    for (int j = 0; j < 8; ++j) {
      float qf = bf2f(q8[j]);
      s0 += qf * bf2f(k0[j]);
      s1 += qf * bf2f(k1[j]);
      s2 += qf * bf2f(k2[j]);
      s3 += qf * bf2f(k3[j]);
    }
  }
  const float scale = 0.10206207261596575f;  // 1/sqrt(96)
  s0 *= scale; s1 *= scale; s2 *= scale; s3 *= scale;
  float m = fmaxf(fmaxf(s0, s1), fmaxf(s2, s3));
  float e0 = __expf(s0 - m), e1 = __expf(s1 - m), e2 = __expf(s2 - m), e3 = __expf(s3 - m);
  float inv = 1.0f / (e0 + e1 + e2 + e3);
  e0 *= inv; e1 *= inv; e2 *= inv; e3 *= inv;
  unsigned short* op = o + (size_t)(bp * 4 + vq) * 768 + h * 96;
  #pragma unroll
  for (int c = 0; c < 96; c += 8) {
    us8 v0 = *(const us8*)(vp + c);
    us8 v1 = *(const us8*)(vp + 96 + c);
    us8 v2 = *(const us8*)(vp + 192 + c);
    us8 v3 = *(const us8*)(vp + 288 + c);
    us8 r;
    #pragma unroll
    for (int j = 0; j < 8; ++j) {
      float val = e0 * bf2f(v0[j]) + e1 * bf2f(v1[j]) + e2 * bf2f(v2[j]) + e3 * bf2f(v3[j]);
      r[j] = f2bf(val);
    }
    *(us8*)(op + c) = r;
  }
}

// ---------- launch ----------
extern "C" void kernel_launch(void* const* d_in, const int* in_sizes, int n_in,
                              void* d_out, int out_size, void* d_ws, size_t ws_size,
                              hipStream_t stream) {
  const float* x         = (const float*)d_in[0];
  const float* norm1_w   = (const float*)d_in[2];
  const float* norm1_b   = (const float*)d_in[3];
  const float* in_proj_w = (const float*)d_in[4];
  const float* in_proj_b = (const float*)d_in[5];
  const float* out_w     = (const float*)d_in[6];
  const float* out_b     = (const float*)d_in[7];
  const float* norm2_w   = (const float*)d_in[8];
  const float* norm2_b   = (const float*)d_in[9];
  const float* ffn_w1    = (const float*)d_in[10];
  const float* ffn_b1    = (const float*)d_in[11];
  const float* ffn_w2    = (const float*)d_in[12];
  const float* ffn_b2    = (const float*)d_in[13];
  float* out = (float*)d_out;

  char* ws = (char*)d_ws;
  unsigned short* wq = (unsigned short*)ws;                           // 616.6 MB
  unsigned short* wh = (unsigned short*)(ws + 616562688u);            // 154.1 MB
  unsigned short* wB = (unsigned short*)(ws + 616562688u + 154140672u);
  unsigned short* wIn  = wB;
  unsigned short* wOut = wB + 1769472;
  unsigned short* wF1  = wOut + 589824;
  unsigned short* wF2  = wF1 + 2359296;

  conv_f32_bf16<<<(442368 + 255) / 256, 256, 0, stream>>>(in_proj_w, wIn, 442368);
  conv_f32_bf16<<<(147456 + 255) / 256, 256, 0, stream>>>(out_w, wOut, 147456);
  conv_f32_bf16<<<(589824 + 255) / 256, 256, 0, stream>>>(ffn_w1, wF1, 589824);
  conv_f32_bf16<<<(589824 + 255) / 256, 256, 0, stream>>>(ffn_w2, wF2, 589824);

  // LN1: x (permuted read) -> wh
  ln_kernel<<<25088, 256, 0, stream>>>(x, norm1_w, norm1_b, wh);
  // QKV: wh(100352x768) @ in_proj_w^T -> wq (attention layout)
  gemm_k<768, 0><<<dim3(18, 784), 256, 0, stream>>>(wh, wIn, in_proj_b, (void*)wq, nullptr, 2304);
  // attention: wq -> wh (o, bf16 rows)
  attn_kernel<<<3136, 256, 0, stream>>>(wq, wh);
  // out-proj + residual(x): wh @ out_w^T -> d_out fp32 (unfolded)
  gemm_k<768, 1><<<dim3(6, 784), 256, 0, stream>>>(wh, wOut, out_b, (void*)out, x, 768);
  // LN2: d_out (permuted read) -> wh
  ln_kernel<<<25088, 256, 0, stream>>>(out, norm2_w, norm2_b, wh);
  // FFN1 + gelu: wh @ ffn_w1^T -> wq bf16 row-major
  gemm_k<768, 2><<<dim3(24, 784), 256, 0, stream>>>(wh, wF1, ffn_b1, (void*)wq, nullptr, 3072);
  // FFN2 + residual(d_out): wq(100352x3072) @ ffn_w2^T -> d_out fp32
  gemm_k<3072, 3><<<dim3(6, 784), 256, 0, stream>>>(wq, wF2, ffn_b2, (void*)out, out, 768);

  (void)in_sizes; (void)n_in; (void)out_size; (void)ws_size;
}